// Round 1
// baseline (902.410 us; speedup 1.0000x reference)
//
#include <hip/hip_runtime.h>
#include <stdint.h>

typedef unsigned short u16;
typedef unsigned int u32;
typedef __bf16 bf16x8 __attribute__((ext_vector_type(8)));
typedef float floatx4 __attribute__((ext_vector_type(4)));

static constexpr int NC = 120000;
static constexpr int NF = 240000;

__device__ __forceinline__ float bf2f(u16 u) {
    union { u32 i; float f; } v; v.i = ((u32)u) << 16; return v.f;
}
__device__ __forceinline__ u16 f2bf(float f) {
    union { float f; u32 i; } v; v.f = f;
    u32 r = v.i + 0x7FFFu + ((v.i >> 16) & 1u);
    return (u16)(r >> 16);
}

// xp[i] = bf16(feats_x[i] + feats_skip[i]) for i < NC rows; row NC zeroed (pad row).
__global__ void add_pad_k(const float* __restrict__ a, const float* __restrict__ b,
                          u16* __restrict__ xp) {
    int idx = blockIdx.x * blockDim.x + threadIdx.x;  // 4 elements per thread
    if (idx >= (NC + 1) * 32) return;
    uint2 vo;
    if (idx < NC * 32) {
        float4 va = ((const float4*)a)[idx];
        float4 vb = ((const float4*)b)[idx];
        vo.x = (u32)f2bf(va.x + vb.x) | ((u32)f2bf(va.y + vb.y) << 16);
        vo.y = (u32)f2bf(va.z + vb.z) | ((u32)f2bf(va.w + vb.w) << 16);
    } else {
        vo.x = vo.y = 0u;
    }
    ((uint2*)xp)[idx] = vo;
}

// Fragment-major weight layout: Wt[k][kc][nt][lane][j] = bf16(W[k][ci][co])
// with ci = kc*32 + (lane>>4)*8 + j, co = nt*16 + (lane&15).
// Makes each wave b-fragment load one contiguous 1KB block.
__global__ void transpose_w_k(const float* __restrict__ W, u16* __restrict__ Wt,
                              int K, int Cin) {
    int idx = blockIdx.x * blockDim.x + threadIdx.x;
    if (idx >= K * Cin * 64) return;
    int per = Cin * 64;
    int k = idx / per, rem = idx - k * per;
    int kc = rem >> 11;             // rem / 2048
    int r2 = rem & 2047;
    int nt = r2 >> 9, lane = (r2 >> 3) & 63, j = r2 & 7;
    int ci = kc * 32 + (lane >> 4) * 8 + j;
    int co = nt * 16 + (lane & 15);
    Wt[idx] = f2bf(W[(size_t)(k * Cin + ci) * 64 + co]);
}

// Upsample weights: only 9 of 27 taps can ever be valid (parity structure of the
// k=3,s=2,p=1 inverse conv): sorted slots {0,2,6,8,13,18,20,24,26}.
__device__ __forceinline__ int upslot_to_k(int s) {
    if (s == 4) return 13;
    int e = s < 4 ? s : s - 5;
    int base = s < 4 ? 0 : 18;
    return base + 2 * e + ((e >> 1) << 1);   // {0,2,6,8} / {18,20,24,26}
}
__global__ void transpose_wup_k(const float* __restrict__ W, u16* __restrict__ Wt) {
    int idx = blockIdx.x * blockDim.x + threadIdx.x;
    if (idx >= 9 * 4096) return;
    int s = idx >> 12, rem = idx & 4095;
    int kc = rem >> 11, r2 = rem & 2047;
    int nt = r2 >> 9, lane = (r2 >> 3) & 63, j = r2 & 7;
    int ci = kc * 32 + (lane >> 4) * 8 + j;
    int co = nt * 16 + (lane & 15);
    int k = upslot_to_k(s);
    Wt[idx] = f2bf(W[(size_t)(k * 64 + ci) * 64 + co]);
}

__global__ void fill_k(int* __restrict__ p, int n, int val) {
    int i = blockIdx.x * blockDim.x + threadIdx.x;
    if (i < n) p[i] = val;
}

// inv[k][out] = in  for each valid pair (out indices unique per k).
__global__ void scatter_k(const int* __restrict__ pairs, int* __restrict__ inv,
                          int npairs, int n_out) {
    int i = blockIdx.x * blockDim.x + threadIdx.x;
    if (i >= npairs) return;
    int in = pairs[2 * i], out = pairs[2 * i + 1];
    if (out < n_out) inv[(i / NC) * n_out + out] = in;
}

// Upsample scatter with 27->9 slot compaction (parity-invalid taps never have
// valid pairs; their dummies carry out=NF and are dropped by the guard).
__global__ void scatter_up_k(const int* __restrict__ pairs, int* __restrict__ inv) {
    int i = blockIdx.x * blockDim.x + threadIdx.x;
    if (i >= 27 * NC) return;
    int in = pairs[2 * i], out = pairs[2 * i + 1];
    if (out >= NF) return;
    int k = i / NC;
    int a = k / 9, r = k - a * 9, b = r / 3, c = r - b * 3;
    int s;
    if (k == 13) {
        s = 4;
    } else if (((a | b | c) & 1) == 0) {
        int e = (a >> 1) * 4 + (b >> 1) * 2 + (c >> 1);
        s = e < 4 ? e : e + 1;     // slot 4 is tap 13
    } else {
        return;                    // structurally impossible for a valid pair
    }
    inv[(size_t)s * NF + out] = in;
}

// Barrier-free, register-pipelined gather-GEMM sparse conv.
// Dual problem sets selected by blockIdx (grid concat) to fuse independent convs
// (also used for split-K halves writing separate partial buffers).
// Per wave: R row-tiles of 16 rows x 64 cols. k fully unrolled; A-fragments
// double-buffered in registers (prefetch tap k+1 during tap k's MFMAs); row
// indices prefetched two taps ahead. Per-tile liveness skip (dummy row == NC).
template <int TCIN, int K, int R, bool LEAKY, bool F32OUT, int MINW>
__global__ __launch_bounds__(256, MINW) void spconv_k(
    const u16* __restrict__ feats,
    const int* __restrict__ invA, const u16* __restrict__ wTA, void* __restrict__ outA,
    const int* __restrict__ invB, const u16* __restrict__ wTB, void* __restrict__ outB,
    int nb0, int n_outA, int n_outB) {
    constexpr int KC = TCIN / 32;
    const int tid = threadIdx.x;
    const int wave = tid >> 6, lane = tid & 63;
    const int l15 = lane & 15, quad = lane >> 4;
    const bool second = (int)blockIdx.x >= nb0;
    const int bid = second ? (int)blockIdx.x - nb0 : (int)blockIdx.x;
    const int* __restrict__ inv = second ? invB : invA;
    const u16* __restrict__ wT  = second ? wTB : wTA;
    void* __restrict__ outv     = second ? outB : outA;
    const int n_out             = second ? n_outB : n_outA;

    const int blockrow = bid * (R * 64);
    const int base = blockrow + wave * 16 + l15;

    floatx4 acc[R][4];
#pragma unroll
    for (int t = 0; t < R; ++t)
#pragma unroll
        for (int nt = 0; nt < 4; ++nt) acc[t][nt] = (floatx4)(0.0f);

    int rc[R], rn[R];
#pragma unroll
    for (int t = 0; t < R; ++t) rc[t] = inv[base + t * 64];
#pragma unroll
    for (int t = 0; t < R; ++t) rn[t] = inv[n_out + base + t * 64];

    bf16x8 abuf[2][R][KC];
    // prologue: gather A for tap 0 (live tiles only)
#pragma unroll
    for (int t = 0; t < R; ++t) {
        if (__any(rc[t] != NC)) {
            const u16* ap = feats + (size_t)rc[t] * TCIN + quad * 8;
#pragma unroll
            for (int kc = 0; kc < KC; ++kc) abuf[0][t][kc] = *(const bf16x8*)(ap + kc * 32);
        }
    }

#pragma unroll
    for (int k = 0; k < K; ++k) {
        const int cur = k & 1, nxt = cur ^ 1;
        int rf[R];
#pragma unroll
        for (int t = 0; t < R; ++t) rf[t] = NC;
        if (k + 2 < K) {
            const int* invf = inv + (size_t)(k + 2) * n_out;
#pragma unroll
            for (int t = 0; t < R; ++t) rf[t] = invf[base + t * 64];
        }
        bool lv[R], any = false;
#pragma unroll
        for (int t = 0; t < R; ++t) { lv[t] = __any(rc[t] != NC); any = any || lv[t]; }
        bf16x8 b[KC][4];
        if (any) {
            const u16* wk = wT + (size_t)k * (64 * TCIN);
#pragma unroll
            for (int kc = 0; kc < KC; ++kc)
#pragma unroll
                for (int nt = 0; nt < 4; ++nt)
                    b[kc][nt] = *(const bf16x8*)(wk + ((kc * 4 + nt) * 64 + lane) * 8);
        }
        // prefetch A for tap k+1 into the other buffer (before MFMAs issue)
        if (k + 1 < K) {
#pragma unroll
            for (int t = 0; t < R; ++t) {
                if (__any(rn[t] != NC)) {
                    const u16* ap = feats + (size_t)rn[t] * TCIN + quad * 8;
#pragma unroll
                    for (int kc = 0; kc < KC; ++kc) abuf[nxt][t][kc] = *(const bf16x8*)(ap + kc * 32);
                }
            }
        }
#pragma unroll
        for (int t = 0; t < R; ++t) {
            if (lv[t]) {
#pragma unroll
                for (int kc = 0; kc < KC; ++kc)
#pragma unroll
                    for (int nt = 0; nt < 4; ++nt)
                        acc[t][nt] = __builtin_amdgcn_mfma_f32_16x16x32_bf16(
                            abuf[cur][t][kc], b[kc][nt], acc[t][nt], 0, 0, 0);
            }
        }
#pragma unroll
        for (int t = 0; t < R; ++t) { rc[t] = rn[t]; rn[t] = rf[t]; }
    }
    // C/D layout: col = lane&15, row = quad*4 + reg
#pragma unroll
    for (int t = 0; t < R; ++t) {
#pragma unroll
        for (int nt = 0; nt < 4; ++nt) {
#pragma unroll
            for (int r = 0; r < 4; ++r) {
                float v = acc[t][nt][r];
                if (LEAKY) v = v > 0.f ? v : 0.01f * v;
                int row = blockrow + t * 64 + wave * 16 + quad * 4 + r;
                size_t oi = (size_t)row * 64 + nt * 16 + l15;
                if (F32OUT) ((float*)outv)[oi] = v;
                else        ((u16*)outv)[oi] = f2bf(v);
            }
        }
    }
}

// Per-channel sum/sumsq over two [NC][64] bf16 buffers (grid halves), fp32 accum.
__global__ void stats2_k(const u16* __restrict__ ra, const u16* __restrict__ rb,
                         float* __restrict__ sa, float* __restrict__ sb, int half) {
    const u16* raw = ((int)blockIdx.x < half) ? ra : rb;
    float* sums    = ((int)blockIdx.x < half) ? sa : sb;
    int bx = ((int)blockIdx.x < half) ? (int)blockIdx.x : (int)blockIdx.x - half;
    int tid = threadIdx.x;
    int wave = tid >> 6, c = tid & 63;
    int gw = bx * 4 + wave;
    int GW = half * 4;
    float s = 0.f, q = 0.f;
    for (int r = gw; r < NC; r += GW) {
        float v = bf2f(raw[(size_t)r * 64 + c]);
        s += v; q += v * v;
    }
    __shared__ float sbm[4][64], qbm[4][64];
    sbm[wave][c] = s; qbm[wave][c] = q;
    __syncthreads();
    if (tid < 64) {
        float S = sbm[0][tid] + sbm[1][tid] + sbm[2][tid] + sbm[3][tid];
        float Q = qbm[0][tid] + qbm[1][tid] + qbm[2][tid] + qbm[3][tid];
        atomicAdd(&sums[tid], S);
        atomicAdd(&sums[64 + tid], Q);
    }
}

// Per-channel stats over the SUM of two split-K partial buffers, leaky applied.
template <bool F32IN>
__global__ void stats_pair_k(const void* __restrict__ ra, const void* __restrict__ rb,
                             float* __restrict__ sums, int nblk) {
    int tid = threadIdx.x;
    int wave = tid >> 6, c = tid & 63;
    int gw = (int)blockIdx.x * 4 + wave;
    int GW = nblk * 4;
    float s = 0.f, q = 0.f;
    for (int r = gw; r < NC; r += GW) {
        size_t o = (size_t)r * 64 + c;
        float v = F32IN ? (((const float*)ra)[o] + ((const float*)rb)[o])
                        : (bf2f(((const u16*)ra)[o]) + bf2f(((const u16*)rb)[o]));
        v = v > 0.f ? v : 0.01f * v;
        s += v; q += v * v;
    }
    __shared__ float sbm[4][64], qbm[4][64];
    sbm[wave][c] = s; qbm[wave][c] = q;
    __syncthreads();
    if (tid < 64) {
        float S = sbm[0][tid] + sbm[1][tid] + sbm[2][tid] + sbm[3][tid];
        float Q = qbm[0][tid] + qbm[1][tid] + qbm[2][tid] + qbm[3][tid];
        atomicAdd(&sums[tid], S);
        atomicAdd(&sums[64 + tid], Q);
    }
}

// scale = g*rsqrt(var+eps); shift = b - mean*scale  (biased var, matches jnp.var)
__global__ void finalize_k(const float* __restrict__ sums, const float* __restrict__ g,
                           const float* __restrict__ bb, float* __restrict__ scsh) {
    int c = threadIdx.x;
    if (c < 64) {
        float m = sums[c] / (float)NC;
        float v = sums[64 + c] / (float)NC - m * m;
        float sc = g[c] * rsqrtf(v + 1e-5f);
        scsh[c] = sc;
        scsh[64 + c] = bb[c] - m * sc;
    }
}

// upA = bf16(leaky(rawF0+rawF1) * scale + shift); pad row zeroed.
template <bool F32IN>
__global__ void apply_pair_k(const void* __restrict__ ra, const void* __restrict__ rb,
                             const float* __restrict__ scsh, u16* __restrict__ up) {
    int idx = blockIdx.x * blockDim.x + threadIdx.x;
    if (idx >= (NC + 1) * 64) return;
    int c = idx & 63, i = idx >> 6;
    u16 o = 0;
    if (i < NC) {
        float v = F32IN ? (((const float*)ra)[idx] + ((const float*)rb)[idx])
                        : (bf2f(((const u16*)ra)[idx]) + bf2f(((const u16*)rb)[idx]));
        v = v > 0.f ? v : 0.01f * v;
        o = f2bf(v * scsh[c] + scsh[64 + c]);
    }
    up[idx] = o;
}

__global__ void apply12_k(const u16* __restrict__ rb, const u16* __restrict__ rc,
                          const float* __restrict__ s1, const float* __restrict__ s2,
                          u16* __restrict__ up) {
    int idx = blockIdx.x * blockDim.x + threadIdx.x;
    if (idx >= (NC + 1) * 64) return;
    int c = idx & 63, i = idx >> 6;
    float v = bf2f(rb[idx]) * s1[c] + s1[64 + c] + bf2f(rc[idx]) * s2[c] + s2[64 + c];
    up[idx] = (i < NC) ? f2bf(v) : (u16)0;
}

extern "C" void kernel_launch(void* const* d_in, const int* in_sizes, int n_in,
                              void* d_out, int out_size, void* d_ws, size_t ws_size,
                              hipStream_t stream) {
    const float* feats_x    = (const float*)d_in[0];
    const float* feats_skip = (const float*)d_in[1];
    const float* W_trans    = (const float*)d_in[2];
    const float* W1         = (const float*)d_in[3];
    const float* W2         = (const float*)d_in[4];
    const float* W_up       = (const float*)d_in[5];
    const float* g0 = (const float*)d_in[6],  *b0 = (const float*)d_in[7];
    const float* g1 = (const float*)d_in[8],  *b1 = (const float*)d_in[9];
    const float* g2 = (const float*)d_in[10], *b2 = (const float*)d_in[11];
    const int* pairs33 = (const int*)d_in[12];
    const int* pairs13 = (const int*)d_in[13];
    const int* pairs31 = (const int*)d_in[14];
    const int* pairs_up = (const int*)d_in[15];
    float* outp = (float*)d_out;   // reference output dtype: float32

    // fp32 split-K partials need 124.2 MiB of ws; fall back to bf16 partials
    // (old footprint ~95 MiB) if the workspace is smaller.
    const bool bigws = ws_size >= (size_t)130267392;

    char* ws = (char*)d_ws;
    size_t off = 0;
    auto alloc = [&](size_t bytes) {
        char* p = ws + off;
        off += (bytes + 255) & ~(size_t)255;
        return p;
    };
    u16* xp    = (u16*)alloc(30720256);   // [NC+1][128] bf16; later overlaid by inv_up
    int* inv33 = (int*)alloc(13440000);   // [28][NC] (tap 27 = split-K pad, all dummy)
    int* inv13 = (int*)alloc(4320000);    // [9][NC]  (contiguous with inv33)
    int* inv31 = (int*)alloc(4320000);    // [9][NC]  (contiguous)
    void* rawF0 = (void*)alloc(bigws ? 30720000 : 15360000);  // split-K partial 0
    void* rawF1 = (void*)alloc(bigws ? 30720000 : 15360000);  // split-K partial 1
    u16* upA   = (u16*)alloc(15360128);   // [NC+1][64]
    u16* WtA   = (u16*)alloc(27 * 128 * 64 * 2);
    u16* Wt1   = (u16*)alloc(9 * 64 * 64 * 2);
    u16* Wt2   = (u16*)alloc(9 * 64 * 64 * 2);
    u16* WtU   = (u16*)alloc(9 * 64 * 64 * 2);   // 9 parity-valid slots only
    float* stats = (float*)alloc(6 * 128 * 4);
    int* inv_up = (int*)xp;               // [9][NF] = 8.64MB — xp dead after convA
    u16* rawB = (u16*)rawF0;              // rawF0/1 dead after apply_pair
    u16* rawC = (u16*)rawF1;
    u16* upE  = (u16*)inv33;              // inv33+inv13 dead after convB/C
    float *sums0 = stats,        *sums1 = stats + 128, *sums2 = stats + 256;
    float *scsh0 = stats + 384,  *scsh1 = stats + 512, *scsh2 = stats + 640;

    const int B = 256;
    hipMemsetAsync(stats, 0, 6 * 128 * 4, stream);

    transpose_w_k<<<(27 * 128 * 64 + 255) / 256, B, 0, stream>>>(W_trans, WtA, 27, 128);
    transpose_w_k<<<(9 * 64 * 64 + 255) / 256, B, 0, stream>>>(W1, Wt1, 9, 64);
    transpose_w_k<<<(9 * 64 * 64 + 255) / 256, B, 0, stream>>>(W2, Wt2, 9, 64);
    transpose_wup_k<<<(9 * 64 * 64 + 255) / 256, B, 0, stream>>>(W_up, WtU);

    add_pad_k<<<((NC + 1) * 32 + 255) / 256, B, 0, stream>>>(feats_x, feats_skip, xp);

    // inv33(28 taps)/inv13/inv31 are contiguous: one fill over 46*NC ints
    fill_k<<<(46 * NC + 255) / 256, B, 0, stream>>>(inv33, 46 * NC, NC);
    scatter_k<<<(27 * NC + 255) / 256, B, 0, stream>>>(pairs33, inv33, 27 * NC, NC);
    scatter_k<<<(9 * NC + 255) / 256, B, 0, stream>>>(pairs13, inv13, 9 * NC, NC);
    scatter_k<<<(9 * NC + 255) / 256, B, 0, stream>>>(pairs31, inv31, 9 * NC, NC);

    // conv_trans (27 taps, Cin=128) split-K: taps 0-13 -> rawF0, taps 14-27(pad) ->
    // rawF1, fused in one dispatch via grid concat. 1250 blocks (was 625) to fix
    // the 2.4-blocks/CU occupancy starvation. Leaky moved to the pair readers.
    if (bigws) {
        spconv_k<128, 14, 3, false, true, 4><<<1250, B, 0, stream>>>(
            xp, inv33, WtA, rawF0, inv33 + 14 * NC, WtA + 14 * 128 * 64, rawF1,
            625, NC, NC);
        stats_pair_k<true><<<240, B, 0, stream>>>(rawF0, rawF1, sums0, 240);
        finalize_k<<<1, 64, 0, stream>>>(sums0, g0, b0, scsh0);
        apply_pair_k<true><<<((NC + 1) * 64 + 255) / 256, B, 0, stream>>>(
            rawF0, rawF1, scsh0, upA);
    } else {
        spconv_k<128, 14, 3, false, false, 4><<<1250, B, 0, stream>>>(
            xp, inv33, WtA, rawF0, inv33 + 14 * NC, WtA + 14 * 128 * 64, rawF1,
            625, NC, NC);
        stats_pair_k<false><<<240, B, 0, stream>>>(rawF0, rawF1, sums0, 240);
        finalize_k<<<1, 64, 0, stream>>>(sums0, g0, b0, scsh0);
        apply_pair_k<false><<<((NC + 1) * 64 + 255) / 256, B, 0, stream>>>(
            rawF0, rawF1, scsh0, upA);
    }

    // xp dead — build compacted 9-slot upsample inverse map in its region
    fill_k<<<(9 * NF + 255) / 256, B, 0, stream>>>(inv_up, 9 * NF, NC);
    scatter_up_k<<<(27 * NC + 255) / 256, B, 0, stream>>>(pairs_up, inv_up);

    // conv1x3 + conv3x1 fused via grid concat: 625 + 625 blocks
    spconv_k<64, 9, 3, false, false, 3><<<1250, B, 0, stream>>>(
        upA, inv13, Wt1, rawB, inv31, Wt2, rawC, 625, NC, NC);
    stats2_k<<<240, B, 0, stream>>>(rawB, rawC, sums1, sums2, 120);
    finalize_k<<<1, 64, 0, stream>>>(sums1, g1, b1, scsh1);
    finalize_k<<<1, 64, 0, stream>>>(sums2, g2, b2, scsh2);

    apply12_k<<<((NC + 1) * 64 + 255) / 256, B, 0, stream>>>(rawB, rawC, scsh1, scsh2, upE);

    // upsample inverse conv (9 parity-valid taps, Cin=64) -> d_out (float32)
    // 1250 blocks x 192 rows = 240000.
    spconv_k<64, 9, 3, false, true, 3><<<1250, B, 0, stream>>>(
        upE, inv_up, WtU, outp, inv_up, WtU, outp, 1250, NF, NF);
}

// Round 2
// 540.662 us; speedup vs baseline: 1.6691x; 1.6691x over previous
//
#include <hip/hip_runtime.h>
#include <stdint.h>

typedef unsigned short u16;
typedef unsigned int u32;
typedef __bf16 bf16x8 __attribute__((ext_vector_type(8)));
typedef float floatx4 __attribute__((ext_vector_type(4)));

static constexpr int NC = 120000;
static constexpr int NF = 240000;

__device__ __forceinline__ float bf2f(u16 u) {
    union { u32 i; float f; } v; v.i = ((u32)u) << 16; return v.f;
}
__device__ __forceinline__ u16 f2bf(float f) {
    union { float f; u32 i; } v; v.f = f;
    u32 r = v.i + 0x7FFFu + ((v.i >> 16) & 1u);
    return (u16)(r >> 16);
}

// xp[i] = bf16(feats_x[i] + feats_skip[i]) for i < NC rows; row NC zeroed (pad row).
__global__ void add_pad_k(const float* __restrict__ a, const float* __restrict__ b,
                          u16* __restrict__ xp) {
    int idx = blockIdx.x * blockDim.x + threadIdx.x;  // 4 elements per thread
    if (idx >= (NC + 1) * 32) return;
    uint2 vo;
    if (idx < NC * 32) {
        float4 va = ((const float4*)a)[idx];
        float4 vb = ((const float4*)b)[idx];
        vo.x = (u32)f2bf(va.x + vb.x) | ((u32)f2bf(va.y + vb.y) << 16);
        vo.y = (u32)f2bf(va.z + vb.z) | ((u32)f2bf(va.w + vb.w) << 16);
    } else {
        vo.x = vo.y = 0u;
    }
    ((uint2*)xp)[idx] = vo;
}

// Fragment-major weight layout: Wt[k][kc][nt][lane][j] = bf16(W[k][ci][co])
// with ci = kc*32 + (lane>>4)*8 + j, co = nt*16 + (lane&15).
// Makes each wave b-fragment load one contiguous 1KB block.
__global__ void transpose_w_k(const float* __restrict__ W, u16* __restrict__ Wt,
                              int K, int Cin) {
    int idx = blockIdx.x * blockDim.x + threadIdx.x;
    if (idx >= K * Cin * 64) return;
    int per = Cin * 64;
    int k = idx / per, rem = idx - k * per;
    int kc = rem >> 11;             // rem / 2048
    int r2 = rem & 2047;
    int nt = r2 >> 9, lane = (r2 >> 3) & 63, j = r2 & 7;
    int ci = kc * 32 + (lane >> 4) * 8 + j;
    int co = nt * 16 + (lane & 15);
    Wt[idx] = f2bf(W[(size_t)(k * Cin + ci) * 64 + co]);
}

// Upsample weights: only 9 of 27 taps can ever be valid (parity structure of the
// k=3,s=2,p=1 inverse conv): sorted slots {0,2,6,8,13,18,20,24,26}.
__device__ __forceinline__ int upslot_to_k(int s) {
    if (s == 4) return 13;
    int e = s < 4 ? s : s - 5;
    int base = s < 4 ? 0 : 18;
    return base + 2 * e + ((e >> 1) << 1);   // {0,2,6,8} / {18,20,24,26}
}
__global__ void transpose_wup_k(const float* __restrict__ W, u16* __restrict__ Wt) {
    int idx = blockIdx.x * blockDim.x + threadIdx.x;
    if (idx >= 9 * 4096) return;
    int s = idx >> 12, rem = idx & 4095;
    int kc = rem >> 11, r2 = rem & 2047;
    int nt = r2 >> 9, lane = (r2 >> 3) & 63, j = r2 & 7;
    int ci = kc * 32 + (lane >> 4) * 8 + j;
    int co = nt * 16 + (lane & 15);
    int k = upslot_to_k(s);
    Wt[idx] = f2bf(W[(size_t)(k * 64 + ci) * 64 + co]);
}

__global__ void fill_k(int* __restrict__ p, int n, int val) {
    int i = blockIdx.x * blockDim.x + threadIdx.x;
    if (i < n) p[i] = val;
}

// inv[k][out] = in  for each valid pair (out indices unique per k).
__global__ void scatter_k(const int* __restrict__ pairs, int* __restrict__ inv,
                          int npairs, int n_out) {
    int i = blockIdx.x * blockDim.x + threadIdx.x;
    if (i >= npairs) return;
    int in = pairs[2 * i], out = pairs[2 * i + 1];
    if (out < n_out) inv[(i / NC) * n_out + out] = in;
}

// Upsample scatter with 27->9 slot compaction (parity-invalid taps never have
// valid pairs; their dummies carry out=NF and are dropped by the guard).
__global__ void scatter_up_k(const int* __restrict__ pairs, int* __restrict__ inv) {
    int i = blockIdx.x * blockDim.x + threadIdx.x;
    if (i >= 27 * NC) return;
    int in = pairs[2 * i], out = pairs[2 * i + 1];
    if (out >= NF) return;
    int k = i / NC;
    int a = k / 9, r = k - a * 9, b = r / 3, c = r - b * 3;
    int s;
    if (k == 13) {
        s = 4;
    } else if (((a | b | c) & 1) == 0) {
        int e = (a >> 1) * 4 + (b >> 1) * 2 + (c >> 1);
        s = e < 4 ? e : e + 1;     // slot 4 is tap 13
    } else {
        return;                    // structurally impossible for a valid pair
    }
    inv[(size_t)s * NF + out] = in;
}

// Barrier-free, register-pipelined gather-GEMM sparse conv.
// Dual problem sets selected by blockIdx (grid concat) to fuse independent convs
// (also used for split-K halves writing separate partial buffers).
// Per wave: R row-tiles of 16 rows x 64 cols. k fully unrolled; A-fragments
// double-buffered in registers (prefetch tap k+1 during tap k's MFMAs); row
// indices prefetched two taps ahead. Per-tile liveness skip (dummy row == NC).
// MINW=2: this kernel holds ~116 live VGPRs (abuf 96 + acc 48 + b at peak);
// MINW=4 caps the allocator at 128 and forces catastrophic scratch spill
// (measured: WRITE_SIZE 60MB -> 1.02GB, 460us). HW occupancy at VGPR=116 is
// 4 waves/SIMD anyway -- the launch bound must not be tighter than that.
template <int TCIN, int K, int R, bool LEAKY, bool F32OUT, int MINW>
__global__ __launch_bounds__(256, MINW) void spconv_k(
    const u16* __restrict__ feats,
    const int* __restrict__ invA, const u16* __restrict__ wTA, void* __restrict__ outA,
    const int* __restrict__ invB, const u16* __restrict__ wTB, void* __restrict__ outB,
    int nb0, int n_outA, int n_outB) {
    constexpr int KC = TCIN / 32;
    const int tid = threadIdx.x;
    const int wave = tid >> 6, lane = tid & 63;
    const int l15 = lane & 15, quad = lane >> 4;
    const bool second = (int)blockIdx.x >= nb0;
    const int bid = second ? (int)blockIdx.x - nb0 : (int)blockIdx.x;
    const int* __restrict__ inv = second ? invB : invA;
    const u16* __restrict__ wT  = second ? wTB : wTA;
    void* __restrict__ outv     = second ? outB : outA;
    const int n_out             = second ? n_outB : n_outA;

    const int blockrow = bid * (R * 64);
    const int base = blockrow + wave * 16 + l15;

    floatx4 acc[R][4];
#pragma unroll
    for (int t = 0; t < R; ++t)
#pragma unroll
        for (int nt = 0; nt < 4; ++nt) acc[t][nt] = (floatx4)(0.0f);

    int rc[R], rn[R];
#pragma unroll
    for (int t = 0; t < R; ++t) rc[t] = inv[base + t * 64];
#pragma unroll
    for (int t = 0; t < R; ++t) rn[t] = inv[n_out + base + t * 64];

    bf16x8 abuf[2][R][KC];
    // prologue: gather A for tap 0 (live tiles only)
#pragma unroll
    for (int t = 0; t < R; ++t) {
        if (__any(rc[t] != NC)) {
            const u16* ap = feats + (size_t)rc[t] * TCIN + quad * 8;
#pragma unroll
            for (int kc = 0; kc < KC; ++kc) abuf[0][t][kc] = *(const bf16x8*)(ap + kc * 32);
        }
    }

#pragma unroll
    for (int k = 0; k < K; ++k) {
        const int cur = k & 1, nxt = cur ^ 1;
        int rf[R];
#pragma unroll
        for (int t = 0; t < R; ++t) rf[t] = NC;
        if (k + 2 < K) {
            const int* invf = inv + (size_t)(k + 2) * n_out;
#pragma unroll
            for (int t = 0; t < R; ++t) rf[t] = invf[base + t * 64];
        }
        bool lv[R], any = false;
#pragma unroll
        for (int t = 0; t < R; ++t) { lv[t] = __any(rc[t] != NC); any = any || lv[t]; }
        bf16x8 b[KC][4];
        if (any) {
            const u16* wk = wT + (size_t)k * (64 * TCIN);
#pragma unroll
            for (int kc = 0; kc < KC; ++kc)
#pragma unroll
                for (int nt = 0; nt < 4; ++nt)
                    b[kc][nt] = *(const bf16x8*)(wk + ((kc * 4 + nt) * 64 + lane) * 8);
        }
        // prefetch A for tap k+1 into the other buffer (before MFMAs issue)
        if (k + 1 < K) {
#pragma unroll
            for (int t = 0; t < R; ++t) {
                if (__any(rn[t] != NC)) {
                    const u16* ap = feats + (size_t)rn[t] * TCIN + quad * 8;
#pragma unroll
                    for (int kc = 0; kc < KC; ++kc) abuf[nxt][t][kc] = *(const bf16x8*)(ap + kc * 32);
                }
            }
        }
#pragma unroll
        for (int t = 0; t < R; ++t) {
            if (lv[t]) {
#pragma unroll
                for (int kc = 0; kc < KC; ++kc)
#pragma unroll
                    for (int nt = 0; nt < 4; ++nt)
                        acc[t][nt] = __builtin_amdgcn_mfma_f32_16x16x32_bf16(
                            abuf[cur][t][kc], b[kc][nt], acc[t][nt], 0, 0, 0);
            }
        }
#pragma unroll
        for (int t = 0; t < R; ++t) { rc[t] = rn[t]; rn[t] = rf[t]; }
    }
    // C/D layout: col = lane&15, row = quad*4 + reg
#pragma unroll
    for (int t = 0; t < R; ++t) {
#pragma unroll
        for (int nt = 0; nt < 4; ++nt) {
#pragma unroll
            for (int r = 0; r < 4; ++r) {
                float v = acc[t][nt][r];
                if (LEAKY) v = v > 0.f ? v : 0.01f * v;
                int row = blockrow + t * 64 + wave * 16 + quad * 4 + r;
                size_t oi = (size_t)row * 64 + nt * 16 + l15;
                if (F32OUT) ((float*)outv)[oi] = v;
                else        ((u16*)outv)[oi] = f2bf(v);
            }
        }
    }
}

// Per-channel sum/sumsq over two [NC][64] bf16 buffers (grid halves), fp32 accum.
__global__ void stats2_k(const u16* __restrict__ ra, const u16* __restrict__ rb,
                         float* __restrict__ sa, float* __restrict__ sb, int half) {
    const u16* raw = ((int)blockIdx.x < half) ? ra : rb;
    float* sums    = ((int)blockIdx.x < half) ? sa : sb;
    int bx = ((int)blockIdx.x < half) ? (int)blockIdx.x : (int)blockIdx.x - half;
    int tid = threadIdx.x;
    int wave = tid >> 6, c = tid & 63;
    int gw = bx * 4 + wave;
    int GW = half * 4;
    float s = 0.f, q = 0.f;
    for (int r = gw; r < NC; r += GW) {
        float v = bf2f(raw[(size_t)r * 64 + c]);
        s += v; q += v * v;
    }
    __shared__ float sbm[4][64], qbm[4][64];
    sbm[wave][c] = s; qbm[wave][c] = q;
    __syncthreads();
    if (tid < 64) {
        float S = sbm[0][tid] + sbm[1][tid] + sbm[2][tid] + sbm[3][tid];
        float Q = qbm[0][tid] + qbm[1][tid] + qbm[2][tid] + qbm[3][tid];
        atomicAdd(&sums[tid], S);
        atomicAdd(&sums[64 + tid], Q);
    }
}

// Per-channel stats over the SUM of two split-K partial buffers, leaky applied.
template <bool F32IN>
__global__ void stats_pair_k(const void* __restrict__ ra, const void* __restrict__ rb,
                             float* __restrict__ sums, int nblk) {
    int tid = threadIdx.x;
    int wave = tid >> 6, c = tid & 63;
    int gw = (int)blockIdx.x * 4 + wave;
    int GW = nblk * 4;
    float s = 0.f, q = 0.f;
    for (int r = gw; r < NC; r += GW) {
        size_t o = (size_t)r * 64 + c;
        float v = F32IN ? (((const float*)ra)[o] + ((const float*)rb)[o])
                        : (bf2f(((const u16*)ra)[o]) + bf2f(((const u16*)rb)[o]));
        v = v > 0.f ? v : 0.01f * v;
        s += v; q += v * v;
    }
    __shared__ float sbm[4][64], qbm[4][64];
    sbm[wave][c] = s; qbm[wave][c] = q;
    __syncthreads();
    if (tid < 64) {
        float S = sbm[0][tid] + sbm[1][tid] + sbm[2][tid] + sbm[3][tid];
        float Q = qbm[0][tid] + qbm[1][tid] + qbm[2][tid] + qbm[3][tid];
        atomicAdd(&sums[tid], S);
        atomicAdd(&sums[64 + tid], Q);
    }
}

// scale = g*rsqrt(var+eps); shift = b - mean*scale  (biased var, matches jnp.var)
__global__ void finalize_k(const float* __restrict__ sums, const float* __restrict__ g,
                           const float* __restrict__ bb, float* __restrict__ scsh) {
    int c = threadIdx.x;
    if (c < 64) {
        float m = sums[c] / (float)NC;
        float v = sums[64 + c] / (float)NC - m * m;
        float sc = g[c] * rsqrtf(v + 1e-5f);
        scsh[c] = sc;
        scsh[64 + c] = bb[c] - m * sc;
    }
}

// upA = bf16(leaky(rawF0+rawF1) * scale + shift); pad row zeroed.
template <bool F32IN>
__global__ void apply_pair_k(const void* __restrict__ ra, const void* __restrict__ rb,
                             const float* __restrict__ scsh, u16* __restrict__ up) {
    int idx = blockIdx.x * blockDim.x + threadIdx.x;
    if (idx >= (NC + 1) * 64) return;
    int c = idx & 63, i = idx >> 6;
    u16 o = 0;
    if (i < NC) {
        float v = F32IN ? (((const float*)ra)[idx] + ((const float*)rb)[idx])
                        : (bf2f(((const u16*)ra)[idx]) + bf2f(((const u16*)rb)[idx]));
        v = v > 0.f ? v : 0.01f * v;
        o = f2bf(v * scsh[c] + scsh[64 + c]);
    }
    up[idx] = o;
}

__global__ void apply12_k(const u16* __restrict__ rb, const u16* __restrict__ rc,
                          const float* __restrict__ s1, const float* __restrict__ s2,
                          u16* __restrict__ up) {
    int idx = blockIdx.x * blockDim.x + threadIdx.x;
    if (idx >= (NC + 1) * 64) return;
    int c = idx & 63, i = idx >> 6;
    float v = bf2f(rb[idx]) * s1[c] + s1[64 + c] + bf2f(rc[idx]) * s2[c] + s2[64 + c];
    up[idx] = (i < NC) ? f2bf(v) : (u16)0;
}

extern "C" void kernel_launch(void* const* d_in, const int* in_sizes, int n_in,
                              void* d_out, int out_size, void* d_ws, size_t ws_size,
                              hipStream_t stream) {
    const float* feats_x    = (const float*)d_in[0];
    const float* feats_skip = (const float*)d_in[1];
    const float* W_trans    = (const float*)d_in[2];
    const float* W1         = (const float*)d_in[3];
    const float* W2         = (const float*)d_in[4];
    const float* W_up       = (const float*)d_in[5];
    const float* g0 = (const float*)d_in[6],  *b0 = (const float*)d_in[7];
    const float* g1 = (const float*)d_in[8],  *b1 = (const float*)d_in[9];
    const float* g2 = (const float*)d_in[10], *b2 = (const float*)d_in[11];
    const int* pairs33 = (const int*)d_in[12];
    const int* pairs13 = (const int*)d_in[13];
    const int* pairs31 = (const int*)d_in[14];
    const int* pairs_up = (const int*)d_in[15];
    float* outp = (float*)d_out;   // reference output dtype: float32

    // fp32 split-K partials need 124.2 MiB of ws; fall back to bf16 partials
    // (old footprint ~95 MiB) if the workspace is smaller.
    const bool bigws = ws_size >= (size_t)130267392;

    char* ws = (char*)d_ws;
    size_t off = 0;
    auto alloc = [&](size_t bytes) {
        char* p = ws + off;
        off += (bytes + 255) & ~(size_t)255;
        return p;
    };
    u16* xp    = (u16*)alloc(30720256);   // [NC+1][128] bf16; later overlaid by inv_up
    int* inv33 = (int*)alloc(13440000);   // [28][NC] (tap 27 = split-K pad, all dummy)
    int* inv13 = (int*)alloc(4320000);    // [9][NC]  (contiguous with inv33)
    int* inv31 = (int*)alloc(4320000);    // [9][NC]  (contiguous)
    void* rawF0 = (void*)alloc(bigws ? 30720000 : 15360000);  // split-K partial 0
    void* rawF1 = (void*)alloc(bigws ? 30720000 : 15360000);  // split-K partial 1
    u16* upA   = (u16*)alloc(15360128);   // [NC+1][64]
    u16* WtA   = (u16*)alloc(27 * 128 * 64 * 2);
    u16* Wt1   = (u16*)alloc(9 * 64 * 64 * 2);
    u16* Wt2   = (u16*)alloc(9 * 64 * 64 * 2);
    u16* WtU   = (u16*)alloc(9 * 64 * 64 * 2);   // 9 parity-valid slots only
    float* stats = (float*)alloc(6 * 128 * 4);
    int* inv_up = (int*)xp;               // [9][NF] = 8.64MB — xp dead after convA
    u16* rawB = (u16*)rawF0;              // rawF0/1 dead after apply_pair
    u16* rawC = (u16*)rawF1;
    u16* upE  = (u16*)inv33;              // inv33+inv13 dead after convB/C
    float *sums0 = stats,        *sums1 = stats + 128, *sums2 = stats + 256;
    float *scsh0 = stats + 384,  *scsh1 = stats + 512, *scsh2 = stats + 640;

    const int B = 256;
    hipMemsetAsync(stats, 0, 6 * 128 * 4, stream);

    transpose_w_k<<<(27 * 128 * 64 + 255) / 256, B, 0, stream>>>(W_trans, WtA, 27, 128);
    transpose_w_k<<<(9 * 64 * 64 + 255) / 256, B, 0, stream>>>(W1, Wt1, 9, 64);
    transpose_w_k<<<(9 * 64 * 64 + 255) / 256, B, 0, stream>>>(W2, Wt2, 9, 64);
    transpose_wup_k<<<(9 * 64 * 64 + 255) / 256, B, 0, stream>>>(W_up, WtU);

    add_pad_k<<<((NC + 1) * 32 + 255) / 256, B, 0, stream>>>(feats_x, feats_skip, xp);

    // inv33(28 taps)/inv13/inv31 are contiguous: one fill over 46*NC ints
    fill_k<<<(46 * NC + 255) / 256, B, 0, stream>>>(inv33, 46 * NC, NC);
    scatter_k<<<(27 * NC + 255) / 256, B, 0, stream>>>(pairs33, inv33, 27 * NC, NC);
    scatter_k<<<(9 * NC + 255) / 256, B, 0, stream>>>(pairs13, inv13, 9 * NC, NC);
    scatter_k<<<(9 * NC + 255) / 256, B, 0, stream>>>(pairs31, inv31, 9 * NC, NC);

    // conv_trans (27 taps, Cin=128) split-K: taps 0-13 -> rawF0, taps 14-27(pad) ->
    // rawF1, fused in one dispatch via grid concat. 1250 blocks (was 625) to fix
    // the 2.4-blocks/CU occupancy starvation. Leaky moved to the pair readers.
    // MINW must stay 2 (see spconv_k comment): MINW=4 spills ~1GB of scratch.
    if (bigws) {
        spconv_k<128, 14, 3, false, true, 2><<<1250, B, 0, stream>>>(
            xp, inv33, WtA, rawF0, inv33 + 14 * NC, WtA + 14 * 128 * 64, rawF1,
            625, NC, NC);
        stats_pair_k<true><<<240, B, 0, stream>>>(rawF0, rawF1, sums0, 240);
        finalize_k<<<1, 64, 0, stream>>>(sums0, g0, b0, scsh0);
        apply_pair_k<true><<<((NC + 1) * 64 + 255) / 256, B, 0, stream>>>(
            rawF0, rawF1, scsh0, upA);
    } else {
        spconv_k<128, 14, 3, false, false, 2><<<1250, B, 0, stream>>>(
            xp, inv33, WtA, rawF0, inv33 + 14 * NC, WtA + 14 * 128 * 64, rawF1,
            625, NC, NC);
        stats_pair_k<false><<<240, B, 0, stream>>>(rawF0, rawF1, sums0, 240);
        finalize_k<<<1, 64, 0, stream>>>(sums0, g0, b0, scsh0);
        apply_pair_k<false><<<((NC + 1) * 64 + 255) / 256, B, 0, stream>>>(
            rawF0, rawF1, scsh0, upA);
    }

    // xp dead — build compacted 9-slot upsample inverse map in its region
    fill_k<<<(9 * NF + 255) / 256, B, 0, stream>>>(inv_up, 9 * NF, NC);
    scatter_up_k<<<(27 * NC + 255) / 256, B, 0, stream>>>(pairs_up, inv_up);

    // conv1x3 + conv3x1 fused via grid concat: 625 + 625 blocks
    spconv_k<64, 9, 3, false, false, 3><<<1250, B, 0, stream>>>(
        upA, inv13, Wt1, rawB, inv31, Wt2, rawC, 625, NC, NC);
    stats2_k<<<240, B, 0, stream>>>(rawB, rawC, sums1, sums2, 120);
    finalize_k<<<1, 64, 0, stream>>>(sums1, g1, b1, scsh1);
    finalize_k<<<1, 64, 0, stream>>>(sums2, g2, b2, scsh2);

    apply12_k<<<((NC + 1) * 64 + 255) / 256, B, 0, stream>>>(rawB, rawC, scsh1, scsh2, upE);

    // upsample inverse conv (9 parity-valid taps, Cin=64) -> d_out (float32)
    // 1250 blocks x 192 rows = 240000.
    spconv_k<64, 9, 3, false, true, 3><<<1250, B, 0, stream>>>(
        upE, inv_up, WtU, outp, inv_up, WtU, outp, 1250, NF, NF);
}

// Round 3
// 533.264 us; speedup vs baseline: 1.6922x; 1.0139x over previous
//
#include <hip/hip_runtime.h>
#include <stdint.h>

typedef unsigned short u16;
typedef unsigned int u32;
typedef __bf16 bf16x8 __attribute__((ext_vector_type(8)));
typedef float floatx4 __attribute__((ext_vector_type(4)));

static constexpr int NC = 120000;
static constexpr int NF = 240000;

__device__ __forceinline__ float bf2f(u16 u) {
    union { u32 i; float f; } v; v.i = ((u32)u) << 16; return v.f;
}
__device__ __forceinline__ u16 f2bf(float f) {
    union { float f; u32 i; } v; v.f = f;
    u32 r = v.i + 0x7FFFu + ((v.i >> 16) & 1u);
    return (u16)(r >> 16);
}

// xp[i] = bf16(feats_x[i] + feats_skip[i]) for i < NC rows; row NC zeroed (pad row).
__global__ void add_pad_k(const float* __restrict__ a, const float* __restrict__ b,
                          u16* __restrict__ xp) {
    int idx = blockIdx.x * blockDim.x + threadIdx.x;  // 4 elements per thread
    if (idx >= (NC + 1) * 32) return;
    uint2 vo;
    if (idx < NC * 32) {
        float4 va = ((const float4*)a)[idx];
        float4 vb = ((const float4*)b)[idx];
        vo.x = (u32)f2bf(va.x + vb.x) | ((u32)f2bf(va.y + vb.y) << 16);
        vo.y = (u32)f2bf(va.z + vb.z) | ((u32)f2bf(va.w + vb.w) << 16);
    } else {
        vo.x = vo.y = 0u;
    }
    ((uint2*)xp)[idx] = vo;
}

// Fragment-major weight layout: Wt[k][kc][nt][lane][j] = bf16(W[k][ci][co])
// with ci = kc*32 + (lane>>4)*8 + j, co = nt*16 + (lane&15).
// Each wave b-fragment load = one contiguous 1KB block; LDS staging mirrors this.
__global__ void transpose_w_k(const float* __restrict__ W, u16* __restrict__ Wt,
                              int K, int Cin) {
    int idx = blockIdx.x * blockDim.x + threadIdx.x;
    if (idx >= K * Cin * 64) return;
    int per = Cin * 64;
    int k = idx / per, rem = idx - k * per;
    int kc = rem >> 11;             // rem / 2048
    int r2 = rem & 2047;
    int nt = r2 >> 9, lane = (r2 >> 3) & 63, j = r2 & 7;
    int ci = kc * 32 + (lane >> 4) * 8 + j;
    int co = nt * 16 + (lane & 15);
    Wt[idx] = f2bf(W[(size_t)(k * Cin + ci) * 64 + co]);
}

// Upsample slots (parity structure of k=3,s=2,p=1 inverse conv):
// slot 0 = tap 13 (even fine rows, identity map); slots 1..8 = even taps
// k = 18*((e>>2)&1) + 6*((e>>1)&1) + 2*(e&1), e = s-1 (odd fine rows).
__device__ __forceinline__ int upslot_to_k(int s) {
    if (s == 0) return 13;
    int e = s - 1;
    return 18 * ((e >> 2) & 1) + 6 * ((e >> 1) & 1) + 2 * (e & 1);
}
__global__ void transpose_wup_k(const float* __restrict__ W, u16* __restrict__ Wt) {
    int idx = blockIdx.x * blockDim.x + threadIdx.x;
    if (idx >= 9 * 4096) return;
    int s = idx >> 12, rem = idx & 4095;
    int kc = rem >> 11, r2 = rem & 2047;
    int nt = r2 >> 9, lane = (r2 >> 3) & 63, j = r2 & 7;
    int ci = kc * 32 + (lane >> 4) * 8 + j;
    int co = nt * 16 + (lane & 15);
    int k = upslot_to_k(s);
    Wt[idx] = f2bf(W[(size_t)(k * 64 + ci) * 64 + co]);
}

__global__ void fill_k(int* __restrict__ p, int n, int val) {
    int i = blockIdx.x * blockDim.x + threadIdx.x;
    if (i < n) p[i] = val;
}

// inv[k][out] = in  for each valid pair (out indices unique per k).
__global__ void scatter_k(const int* __restrict__ pairs, int* __restrict__ inv,
                          int npairs, int n_out) {
    int i = blockIdx.x * blockDim.x + threadIdx.x;
    if (i >= npairs) return;
    int in = pairs[2 * i], out = pairs[2 * i + 1];
    if (out < n_out) inv[(i / NC) * n_out + out] = in;
}

// Upsample scatter with 27->9 slot compaction. slot 0 = tap 13; slots 1..8 =
// even-parity taps (only these can ever have valid pairs).
__global__ void scatter_up_k(const int* __restrict__ pairs, int* __restrict__ inv) {
    int i = blockIdx.x * blockDim.x + threadIdx.x;
    if (i >= 27 * NC) return;
    int in = pairs[2 * i], out = pairs[2 * i + 1];
    if (out >= NF) return;
    int k = i / NC;
    int a = k / 9, r = k - a * 9, b = r / 3, c = r - b * 3;
    int s;
    if (k == 13) {
        s = 0;
    } else if (((a | b | c) & 1) == 0) {
        s = 1 + (a >> 1) * 4 + (b >> 1) * 2 + (c >> 1);
    } else {
        return;                    // structurally impossible for a valid pair
    }
    inv[(size_t)s * NF + out] = in;
}

// Barrier-synced, LDS-weight-staged gather-GEMM sparse conv.
// Dual problem sets selected by blockIdx (grid concat); runtime Klive per problem.
// Per wave: R row-tiles of 16 rows x 64 cols. A-fragments double-buffered in
// registers (prefetch tap k+1 during tap k's MFMAs); row indices prefetched two
// taps ahead. Weights double-buffered in LDS: staged cooperatively once per
// BLOCK per tap (was: per WAVE via L1 -- the 4x weight re-read through the
// ~64B/cy L1 port capped MfmaUtil at ~23%, measured 19%). ds_read_b128 feeds
// the MFMAs from the separate LDS pipe instead.
// MINW=2 for the Cin=128 instance: ~116 live VGPRs; tighter bounds spill
// (measured round 1: MINW=4 -> 1GB scratch traffic).
template <int TCIN, int KMAX, int R, bool F32OUT, int MINW>
__global__ __launch_bounds__(256, MINW) void spconv_k(
    const u16* __restrict__ feats,
    const int* __restrict__ invA, const u16* __restrict__ wTA, void* __restrict__ outA,
    const int* __restrict__ invB, const u16* __restrict__ wTB, void* __restrict__ outB,
    int nb0, int n_outA, int n_outB, int kliveA, int kliveB) {
    constexpr int KC = TCIN / 32;
    constexpr int WFRAGS = TCIN * 64 / 8;      // bf16x8 frags per tap (1024 / 512)
    constexpr int NST = WFRAGS / 256;          // staging chunks per thread (4 / 2)
    __shared__ bf16x8 wlds[2][WFRAGS];

    const int tid = threadIdx.x;
    const int wave = tid >> 6, lane = tid & 63;
    const int l15 = lane & 15, quad = lane >> 4;
    const bool second = (int)blockIdx.x >= nb0;
    const int bid = second ? (int)blockIdx.x - nb0 : (int)blockIdx.x;
    const int* __restrict__ inv = second ? invB : invA;
    const u16* __restrict__ wT  = second ? wTB : wTA;
    void* __restrict__ outv     = second ? outB : outA;
    const int n_out             = second ? n_outB : n_outA;
    const int Klive             = second ? kliveB : kliveA;

    const int blockrow = bid * (R * 64);
    const int base = blockrow + wave * 16 + l15;

    floatx4 acc[R][4];
#pragma unroll
    for (int t = 0; t < R; ++t)
#pragma unroll
        for (int nt = 0; nt < 4; ++nt) acc[t][nt] = (floatx4)(0.0f);

    int rc[R], rn[R];
#pragma unroll
    for (int t = 0; t < R; ++t) rc[t] = inv[base + t * 64];
#pragma unroll
    for (int t = 0; t < R; ++t) rn[t] = inv[n_out + base + t * 64];

    // stage weights for tap 0 into wlds[0] (cooperative, coalesced)
    {
        const bf16x8* wsrc = (const bf16x8*)wT + tid;
#pragma unroll
        for (int s = 0; s < NST; ++s) wlds[0][tid + s * 256] = wsrc[s * 256];
    }

    bf16x8 abuf[2][R][KC];
    // prologue: gather A for tap 0 (live tiles only)
#pragma unroll
    for (int t = 0; t < R; ++t) {
        if (__any(rc[t] != NC)) {
            const u16* ap = feats + (size_t)rc[t] * TCIN + quad * 8;
#pragma unroll
            for (int kc = 0; kc < KC; ++kc) abuf[0][t][kc] = *(const bf16x8*)(ap + kc * 32);
        }
    }
    __syncthreads();

#pragma unroll
    for (int k = 0; k < KMAX; ++k) {
        if (k < Klive) {
            const int cur = k & 1, nxt = cur ^ 1;
            // stage weights for tap k+1 into the other LDS buffer
            if (k + 1 < Klive) {
                const bf16x8* wsrc = (const bf16x8*)(wT + (size_t)(k + 1) * (64 * TCIN)) + tid;
                bf16x8 st[NST];
#pragma unroll
                for (int s = 0; s < NST; ++s) st[s] = wsrc[s * 256];
#pragma unroll
                for (int s = 0; s < NST; ++s) wlds[nxt][tid + s * 256] = st[s];
            }
            int rf[R];
#pragma unroll
            for (int t = 0; t < R; ++t) rf[t] = NC;
            if (k + 2 < Klive) {
                const int* invf = inv + (size_t)(k + 2) * n_out;
#pragma unroll
                for (int t = 0; t < R; ++t) rf[t] = invf[base + t * 64];
            }
            bool lv[R], any = false;
#pragma unroll
            for (int t = 0; t < R; ++t) { lv[t] = __any(rc[t] != NC); any = any || lv[t]; }
            // prefetch A for tap k+1 into the other register buffer
            if (k + 1 < Klive) {
#pragma unroll
                for (int t = 0; t < R; ++t) {
                    if (__any(rn[t] != NC)) {
                        const u16* ap = feats + (size_t)rn[t] * TCIN + quad * 8;
#pragma unroll
                        for (int kc = 0; kc < KC; ++kc)
                            abuf[nxt][t][kc] = *(const bf16x8*)(ap + kc * 32);
                    }
                }
            }
            if (any) {
                bf16x8 b[KC][4];
#pragma unroll
                for (int kc = 0; kc < KC; ++kc)
#pragma unroll
                    for (int nt = 0; nt < 4; ++nt)
                        b[kc][nt] = wlds[cur][(kc * 4 + nt) * 64 + lane];
#pragma unroll
                for (int t = 0; t < R; ++t) {
                    if (lv[t]) {
#pragma unroll
                        for (int kc = 0; kc < KC; ++kc)
#pragma unroll
                            for (int nt = 0; nt < 4; ++nt)
                                acc[t][nt] = __builtin_amdgcn_mfma_f32_16x16x32_bf16(
                                    abuf[cur][t][kc], b[kc][nt], acc[t][nt], 0, 0, 0);
                    }
                }
            }
            __syncthreads();
#pragma unroll
            for (int t = 0; t < R; ++t) { rc[t] = rn[t]; rn[t] = rf[t]; }
        }
    }
    // C/D layout: col = lane&15, row = quad*4 + reg
#pragma unroll
    for (int t = 0; t < R; ++t) {
#pragma unroll
        for (int nt = 0; nt < 4; ++nt) {
#pragma unroll
            for (int r = 0; r < 4; ++r) {
                float v = acc[t][nt][r];
                int row = blockrow + t * 64 + wave * 16 + quad * 4 + r;
                size_t oi = (size_t)row * 64 + nt * 16 + l15;
                if (F32OUT) ((float*)outv)[oi] = v;
                else        ((u16*)outv)[oi] = f2bf(v);
            }
        }
    }
}

// Per-channel sum/sumsq over two [NC][64] bf16 buffers (grid halves), fp32 accum.
__global__ void stats2_k(const u16* __restrict__ ra, const u16* __restrict__ rb,
                         float* __restrict__ sa, float* __restrict__ sb, int half) {
    const u16* raw = ((int)blockIdx.x < half) ? ra : rb;
    float* sums    = ((int)blockIdx.x < half) ? sa : sb;
    int bx = ((int)blockIdx.x < half) ? (int)blockIdx.x : (int)blockIdx.x - half;
    int tid = threadIdx.x;
    int wave = tid >> 6, c = tid & 63;
    int gw = bx * 4 + wave;
    int GW = half * 4;
    float s = 0.f, q = 0.f;
    for (int r = gw; r < NC; r += GW) {
        float v = bf2f(raw[(size_t)r * 64 + c]);
        s += v; q += v * v;
    }
    __shared__ float sbm[4][64], qbm[4][64];
    sbm[wave][c] = s; qbm[wave][c] = q;
    __syncthreads();
    if (tid < 64) {
        float S = sbm[0][tid] + sbm[1][tid] + sbm[2][tid] + sbm[3][tid];
        float Q = qbm[0][tid] + qbm[1][tid] + qbm[2][tid] + qbm[3][tid];
        atomicAdd(&sums[tid], S);
        atomicAdd(&sums[64 + tid], Q);
    }
}

// Per-channel stats over the SUM of two split-K partial buffers, leaky applied.
template <bool F32IN>
__global__ void stats_pair_k(const void* __restrict__ ra, const void* __restrict__ rb,
                             float* __restrict__ sums, int nblk) {
    int tid = threadIdx.x;
    int wave = tid >> 6, c = tid & 63;
    int gw = (int)blockIdx.x * 4 + wave;
    int GW = nblk * 4;
    float s = 0.f, q = 0.f;
    for (int r = gw; r < NC; r += GW) {
        size_t o = (size_t)r * 64 + c;
        float v = F32IN ? (((const float*)ra)[o] + ((const float*)rb)[o])
                        : (bf2f(((const u16*)ra)[o]) + bf2f(((const u16*)rb)[o]));
        v = v > 0.f ? v : 0.01f * v;
        s += v; q += v * v;
    }
    __shared__ float sbm[4][64], qbm[4][64];
    sbm[wave][c] = s; qbm[wave][c] = q;
    __syncthreads();
    if (tid < 64) {
        float S = sbm[0][tid] + sbm[1][tid] + sbm[2][tid] + sbm[3][tid];
        float Q = qbm[0][tid] + qbm[1][tid] + qbm[2][tid] + qbm[3][tid];
        atomicAdd(&sums[tid], S);
        atomicAdd(&sums[64 + tid], Q);
    }
}

// scale = g*rsqrt(var+eps); shift = b - mean*scale  (biased var, matches jnp.var)
__global__ void finalize_k(const float* __restrict__ sums, const float* __restrict__ g,
                           const float* __restrict__ bb, float* __restrict__ scsh) {
    int c = threadIdx.x;
    if (c < 64) {
        float m = sums[c] / (float)NC;
        float v = sums[64 + c] / (float)NC - m * m;
        float sc = g[c] * rsqrtf(v + 1e-5f);
        scsh[c] = sc;
        scsh[64 + c] = bb[c] - m * sc;
    }
}

// upA = bf16(leaky(rawF0+rawF1) * scale + shift); pad row zeroed.
template <bool F32IN>
__global__ void apply_pair_k(const void* __restrict__ ra, const void* __restrict__ rb,
                             const float* __restrict__ scsh, u16* __restrict__ up) {
    int idx = blockIdx.x * blockDim.x + threadIdx.x;
    if (idx >= (NC + 1) * 64) return;
    int c = idx & 63, i = idx >> 6;
    u16 o = 0;
    if (i < NC) {
        float v = F32IN ? (((const float*)ra)[idx] + ((const float*)rb)[idx])
                        : (bf2f(((const u16*)ra)[idx]) + bf2f(((const u16*)rb)[idx]));
        v = v > 0.f ? v : 0.01f * v;
        o = f2bf(v * scsh[c] + scsh[64 + c]);
    }
    up[idx] = o;
}

__global__ void apply12_k(const u16* __restrict__ rb, const u16* __restrict__ rc,
                          const float* __restrict__ s1, const float* __restrict__ s2,
                          u16* __restrict__ up) {
    int idx = blockIdx.x * blockDim.x + threadIdx.x;
    if (idx >= (NC + 1) * 64) return;
    int c = idx & 63, i = idx >> 6;
    float v = bf2f(rb[idx]) * s1[c] + s1[64 + c] + bf2f(rc[idx]) * s2[c] + s2[64 + c];
    up[idx] = (i < NC) ? f2bf(v) : (u16)0;
}

extern "C" void kernel_launch(void* const* d_in, const int* in_sizes, int n_in,
                              void* d_out, int out_size, void* d_ws, size_t ws_size,
                              hipStream_t stream) {
    const float* feats_x    = (const float*)d_in[0];
    const float* feats_skip = (const float*)d_in[1];
    const float* W_trans    = (const float*)d_in[2];
    const float* W1         = (const float*)d_in[3];
    const float* W2         = (const float*)d_in[4];
    const float* W_up       = (const float*)d_in[5];
    const float* g0 = (const float*)d_in[6],  *b0 = (const float*)d_in[7];
    const float* g1 = (const float*)d_in[8],  *b1 = (const float*)d_in[9];
    const float* g2 = (const float*)d_in[10], *b2 = (const float*)d_in[11];
    const int* pairs33 = (const int*)d_in[12];
    const int* pairs13 = (const int*)d_in[13];
    const int* pairs31 = (const int*)d_in[14];
    const int* pairs_up = (const int*)d_in[15];
    float* outp = (float*)d_out;   // reference output dtype: float32

    // fp32 split-K partials need ~124 MiB of ws; fall back to bf16 partials
    // (old footprint ~95 MiB) if the workspace is smaller.
    const bool bigws = ws_size >= (size_t)130267392;

    char* ws = (char*)d_ws;
    size_t off = 0;
    auto alloc = [&](size_t bytes) {
        char* p = ws + off;
        off += (bytes + 255) & ~(size_t)255;
        return p;
    };
    u16* xp    = (u16*)alloc(30720256);   // [NC+1][128] bf16; later overlaid by inv_up
    int* inv33 = (int*)alloc(12960000);   // [27][NC]
    int* inv13 = (int*)alloc(4320000);    // [9][NC]  (contiguous with inv33)
    int* inv31 = (int*)alloc(4320000);    // [9][NC]  (contiguous)
    void* rawF0 = (void*)alloc(bigws ? 30720000 : 15360000);  // split-K partial 0
    void* rawF1 = (void*)alloc(bigws ? 30720000 : 15360000);  // split-K partial 1
    u16* upA   = (u16*)alloc(15360128);   // [NC+1][64]
    u16* WtA   = (u16*)alloc(27 * 128 * 64 * 2);
    u16* Wt1   = (u16*)alloc(9 * 64 * 64 * 2);
    u16* Wt2   = (u16*)alloc(9 * 64 * 64 * 2);
    u16* WtU   = (u16*)alloc(9 * 64 * 64 * 2);   // 9 parity-valid slots only
    float* stats = (float*)alloc(6 * 128 * 4);
    int* inv_up = (int*)xp;               // [9][NF] = 8.64MB — xp dead after convA
    u16* rawB = (u16*)rawF0;              // rawF0/1 dead after apply_pair
    u16* rawC = (u16*)rawF1;
    u16* upE  = (u16*)inv33;              // inv33+inv13 dead after convB/C
    float *sums0 = stats,        *sums1 = stats + 128, *sums2 = stats + 256;
    float *scsh0 = stats + 384,  *scsh1 = stats + 512, *scsh2 = stats + 640;

    const int B = 256;
    hipMemsetAsync(stats, 0, 6 * 128 * 4, stream);

    transpose_w_k<<<(27 * 128 * 64 + 255) / 256, B, 0, stream>>>(W_trans, WtA, 27, 128);
    transpose_w_k<<<(9 * 64 * 64 + 255) / 256, B, 0, stream>>>(W1, Wt1, 9, 64);
    transpose_w_k<<<(9 * 64 * 64 + 255) / 256, B, 0, stream>>>(W2, Wt2, 9, 64);
    transpose_wup_k<<<(9 * 64 * 64 + 255) / 256, B, 0, stream>>>(W_up, WtU);

    add_pad_k<<<((NC + 1) * 32 + 255) / 256, B, 0, stream>>>(feats_x, feats_skip, xp);

    // inv33/inv13/inv31 are contiguous: one fill over 45*NC ints
    fill_k<<<(45 * NC + 255) / 256, B, 0, stream>>>(inv33, 45 * NC, NC);
    scatter_k<<<(27 * NC + 255) / 256, B, 0, stream>>>(pairs33, inv33, 27 * NC, NC);
    scatter_k<<<(9 * NC + 255) / 256, B, 0, stream>>>(pairs13, inv13, 9 * NC, NC);
    scatter_k<<<(9 * NC + 255) / 256, B, 0, stream>>>(pairs31, inv31, 9 * NC, NC);

    // conv_trans (27 taps, Cin=128) split-K via grid concat: taps 0-13 -> rawF0,
    // taps 14-26 -> rawF1. 1250 blocks. Leaky folded into the pair readers.
    if (bigws) {
        spconv_k<128, 14, 3, true, 2><<<1250, B, 0, stream>>>(
            xp, inv33, WtA, rawF0, inv33 + 14 * NC, WtA + 14 * 128 * 64, rawF1,
            625, NC, NC, 14, 13);
        stats_pair_k<true><<<240, B, 0, stream>>>(rawF0, rawF1, sums0, 240);
        finalize_k<<<1, 64, 0, stream>>>(sums0, g0, b0, scsh0);
        apply_pair_k<true><<<((NC + 1) * 64 + 255) / 256, B, 0, stream>>>(
            rawF0, rawF1, scsh0, upA);
    } else {
        spconv_k<128, 14, 3, false, 2><<<1250, B, 0, stream>>>(
            xp, inv33, WtA, rawF0, inv33 + 14 * NC, WtA + 14 * 128 * 64, rawF1,
            625, NC, NC, 14, 13);
        stats_pair_k<false><<<240, B, 0, stream>>>(rawF0, rawF1, sums0, 240);
        finalize_k<<<1, 64, 0, stream>>>(sums0, g0, b0, scsh0);
        apply_pair_k<false><<<((NC + 1) * 64 + 255) / 256, B, 0, stream>>>(
            rawF0, rawF1, scsh0, upA);
    }

    // xp dead — build compacted 9-slot upsample inverse map in its region
    fill_k<<<(9 * NF + 255) / 256, B, 0, stream>>>(inv_up, 9 * NF, NC);
    scatter_up_k<<<(27 * NC + 255) / 256, B, 0, stream>>>(pairs_up, inv_up);

    // conv1x3 + conv3x1 fused via grid concat: 625 + 625 blocks
    spconv_k<64, 9, 3, false, 3><<<1250, B, 0, stream>>>(
        upA, inv13, Wt1, rawB, inv31, Wt2, rawC, 625, NC, NC, 9, 9);
    stats2_k<<<240, B, 0, stream>>>(rawB, rawC, sums1, sums2, 120);
    finalize_k<<<1, 64, 0, stream>>>(sums1, g1, b1, scsh1);
    finalize_k<<<1, 64, 0, stream>>>(sums2, g2, b2, scsh2);

    apply12_k<<<((NC + 1) * 64 + 255) / 256, B, 0, stream>>>(rawB, rawC, scsh1, scsh2, upE);

    // upsample inverse conv -> d_out (float32), regime-split via dual problem:
    //   A: blocks 0-624, fine rows < NC (even parity): 1 tap (slot 0 = tap 13,
    //      identity gather).
    //   B: blocks 625-1249, fine rows >= NC (odd parity): 8 taps (slots 1-8),
    //      inv/out offset by NC.
    spconv_k<64, 8, 3, true, 3><<<1250, B, 0, stream>>>(
        upE, inv_up, WtU, outp,
        inv_up + (size_t)NF + NC, WtU + 64 * 64, (void*)(outp + (size_t)NC * 64),
        625, NF, NF, 1, 8);
}